// Round 4
// baseline (193.353 us; speedup 1.0000x reference)
//
#include <hip/hip_runtime.h>

#define NMOL 16
#define NAT  512
#define NK   27
#define NBLK 64          // 4 blocks per molecule, each on its own CU

// Bit-exact float32 constants matching the numpy reference on host:
//   inv_cell diagonal = 1/20 correctly rounded = 0.05f (0x3D4CCCCD)
//   mask: dist<5.0 with correctly-rounded sqrt  <=>  ss < pred(25.0f) = 0x41C7FFFF
#define SSMAX 24.999998092651367f

__device__ __forceinline__ float wrap1(float v) {
    // proj = rn(v*0.05f); coords in [0,20) => proj<1 => woff=0, frac=proj
    // wrapped = rn(frac*20)
    return __fmul_rn(__fmul_rn(v, 0.05f), 20.0f);
}

// Candidate (unique possible) image per component + exact-mask squared distance
// test. Returns kk in 0..26 on hit, 31 on miss.
__device__ __forceinline__ int probe_code(float wx, float wy, float wz,
                                          float wjx, float wjy, float wjz,
                                          bool self) {
    float dx = __fsub_rn(wx, wjx);
    float dy = __fsub_rn(wy, wjy);
    float dz = __fsub_rn(wz, wjz);
    int ox = (dx > 15.0f) ? -1 : ((dx < -15.0f) ? 1 : 0);
    int oy = (dy > 15.0f) ? -1 : ((dy < -15.0f) ? 1 : 0);
    int oz = (dz > 15.0f) ? -1 : ((dz < -15.0f) ? 1 : 0);
    float ax = __fadd_rn(dx, 20.0f * (float)ox);
    float ay = __fadd_rn(dy, 20.0f * (float)oy);
    float az = __fadd_rn(dz, 20.0f * (float)oz);
    float ss = __fadd_rn(__fadd_rn(__fmul_rn(ax, ax), __fmul_rn(ay, ay)),
                         __fmul_rn(az, az));
    bool hit = (ss < SSMAX) && !self;
    return hit ? ((ox + 1) * 9 + (oy + 1) * 3 + (oz + 1)) : 31;
}

// Single fused kernel. Block = quarter of a molecule's emit work, but counts
// its WHOLE molecule redundantly in LDS so the chunk scan is block-local.
// Only cross-block data: 16 per-molecule totals -> one 64-arrival barrier.
// LDS: 6KB coords + 55.3KB cnt + small = ~61.7KB (< 64KB static limit).
__global__ __launch_bounds__(1024, 4) void fused(const float* __restrict__ coords,
                                                 int* __restrict__ bar,
                                                 int* __restrict__ totals,
                                                 float* __restrict__ out, int P) {
    __shared__ float rr[NAT * 3];      // raw packed coords of this molecule
    __shared__ int cnt[NK * NAT];      // per-(k,i) counts -> exclusive -> cursors
    __shared__ int ctot[NK];           // chunk totals
    __shared__ int cexcl[NK];          // absolute chunk bases (incl molecule base)
    __shared__ int tls[NMOL];          // molecule totals

    const int blk  = blockIdx.x;
    const int m    = blk >> 2;         // molecule
    const int q    = blk & 3;          // quarter (emit slice)
    const int t    = threadIdx.x;      // 0..1023
    const int w    = t >> 6;           // wave 0..15
    const int lane = t & 63;

    // ---- stage raw coords (packed, float4) + zero counts ----
    const float4* cm4 = reinterpret_cast<const float4*>(coords + (size_t)m * NAT * 3);
    float4* rr4 = reinterpret_cast<float4*>(rr);
    if (t < 384) rr4[t] = cm4[t];
    for (int x = t; x < NK * NAT; x += 1024) cnt[x] = 0;
    __syncthreads();

    // ---- count phase: full molecule, redundant across the 4 sibling blocks ----
    // wave w owns atoms w*32 .. w*32+31, processed 2 at a time sharing wj.
    for (int u = 0; u < 16; ++u) {
        const int iA = w * 32 + 2 * u, iB = iA + 1;
        const float wAx = wrap1(rr[iA*3+0]), wAy = wrap1(rr[iA*3+1]), wAz = wrap1(rr[iA*3+2]);
        const float wBx = wrap1(rr[iB*3+0]), wBy = wrap1(rr[iB*3+1]), wBz = wrap1(rr[iB*3+2]);
        #pragma unroll
        for (int it = 0; it < NAT / 64; ++it) {
            const int j = it * 64 + lane;
            const float wjx = wrap1(rr[j*3+0]);
            const float wjy = wrap1(rr[j*3+1]);
            const float wjz = wrap1(rr[j*3+2]);
            int cA = probe_code(wAx, wAy, wAz, wjx, wjy, wjz, j == iA);
            int cB = probe_code(wBx, wBy, wBz, wjx, wjy, wjz, j == iB);
            if (cA != 31) atomicAdd(&cnt[cA * NAT + iA], 1);
            if (cB != 31) atomicAdd(&cnt[cB * NAT + iB], 1);
        }
    }
    __syncthreads();

    // ---- per-chunk (k over 512 atoms) exclusive scan, one wave per chunk ----
    for (int k = w; k < NK; k += 16) {
        int* ck = cnt + k * NAT;
        int v[8];
        int tot = 0;
        #pragma unroll
        for (int e = 0; e < 8; ++e) { v[e] = ck[lane * 8 + e]; tot += v[e]; }
        int incl = tot;
        #pragma unroll
        for (int d = 1; d < 64; d <<= 1) {      // inclusive wave scan of lane sums
            int uu = __shfl_up(incl, d, 64);
            if (lane >= d) incl += uu;
        }
        int acc = incl - tot;                   // exclusive base of this lane's 8
        #pragma unroll
        for (int e = 0; e < 8; ++e) { int tmp = v[e]; ck[lane * 8 + e] = acc; acc += tmp; }
        if (lane == 63) ctot[k] = incl;         // chunk total
    }
    __syncthreads();

    // ---- publish molecule total, tiny 64-arrival grid barrier, compute bases ----
    if (t == 0) {
        if (q == 0) {
            int mt = 0;
            for (int k = 0; k < NK; ++k) mt += ctot[k];
            __hip_atomic_store(&totals[m], mt, __ATOMIC_RELAXED, __HIP_MEMORY_SCOPE_AGENT);
        }
        __hip_atomic_fetch_add(bar, 1, __ATOMIC_ACQ_REL, __HIP_MEMORY_SCOPE_AGENT);
        while (__hip_atomic_load(bar, __ATOMIC_ACQUIRE, __HIP_MEMORY_SCOPE_AGENT) < NBLK)
            __builtin_amdgcn_s_sleep(2);
    }
    __syncthreads();
    if (t < NMOL)
        tls[t] = __hip_atomic_load(&totals[t], __ATOMIC_RELAXED, __HIP_MEMORY_SCOPE_AGENT);
    __syncthreads();
    if (t == 0) {
        int run = 0;
        for (int mm = 0; mm < m; ++mm) run += tls[mm];   // molecule base
        for (int k = 0; k < NK; ++k) { cexcl[k] = run; run += ctot[k]; }
    }
    __syncthreads();
    // fold absolute bases into cnt -> cnt becomes the global cursor per (k,i)
    for (int x = t; x < NK * NAT; x += 1024) cnt[x] += cexcl[x >> 9];
    __syncthreads();

    // ---- emit phase: this block's quarter (128 atoms), verified ballot order ----
    const unsigned long long ltmask =
        (lane == 0) ? 0ull : (~0ull >> (64 - lane));

    for (int u = 0; u < 8; ++u) {
        const int i  = q * 128 + w * 8 + u;
        const float rx = rr[i*3+0], ry = rr[i*3+1], rz = rr[i*3+2];
        const float wx = wrap1(rx), wy = wrap1(ry), wz = wrap1(rz);
        const int pf = m * NAT + i;

        #pragma unroll
        for (int it = 0; it < NAT / 64; ++it) {
            const int j = it * 64 + lane;
            const float rjx = rr[j*3+0], rjy = rr[j*3+1], rjz = rr[j*3+2];
            int code = probe_code(wx, wy, wz,
                                  wrap1(rjx), wrap1(rjy), wrap1(rjz), j == i);
            bool hit = (code != 31);
            int kk = hit ? code : 0;

            // match-any over 5-bit kk among hitting lanes
            unsigned long long grp = __ballot(hit);
            #pragma unroll
            for (int b = 0; b < 5; ++b) {
                unsigned long long bm = __ballot((kk >> b) & 1);
                grp &= ((kk >> b) & 1) ? bm : ~bm;
            }
            int leader = hit ? (__ffsll((unsigned long long)grp) - 1) : 0;
            int cntg   = __popcll(grp);
            int rank   = __popcll(grp & ltmask);

            int base = 0;
            if (hit && lane == leader)
                base = atomicAdd(&cnt[kk * NAT + i], cntg);   // ds_add_rtn cursor
            base = __shfl(base, leader, 64);                  // broadcast from leader

            if (hit) {
                int p = base + rank;
                if (p < P) {
                    int ox = kk / 9;
                    int rem = kk - ox * 9;
                    int oy = rem / 3;
                    int oz = rem - oy * 3;
                    ox -= 1; oy -= 1; oz -= 1;
                    float cx = 20.0f * (float)ox;
                    float cy = 20.0f * (float)oy;
                    float cz = 20.0f * (float)oz;
                    float px = __fadd_rn(__fsub_rn(rx, rjx), cx);
                    float py = __fadd_rn(__fsub_rn(ry, rjy), cy);
                    float pz = __fadd_rn(__fsub_rn(rz, rjz), cz);
                    float ss = __fadd_rn(__fadd_rn(__fmul_rn(px, px), __fmul_rn(py, py)),
                                         __fmul_rn(pz, pz));
                    out[p]                 = __fsqrt_rn(ss);        // distflat2
                    out[P + p]             = (float)pf;             // pair_first
                    out[2 * P + p]         = (float)(m * NAT + j);  // pair_second
                    out[3 * P + 3 * p + 0] = px;                    // paircoord
                    out[3 * P + 3 * p + 1] = py;
                    out[3 * P + 3 * p + 2] = pz;
                    out[6 * P + 3 * p + 0] = (float)ox;             // offsets
                    out[6 * P + 3 * p + 1] = (float)oy;
                    out[6 * P + 3 * p + 2] = (float)oz;
                    out[9 * P + p]         = (float)kk;             // offset_index
                }
            }
        }
    }
}

extern "C" void kernel_launch(void* const* d_in, const int* in_sizes, int n_in,
                              void* d_out, int out_size, void* d_ws, size_t ws_size,
                              hipStream_t stream) {
    (void)in_sizes; (void)n_in; (void)ws_size;
    const float* coords = (const float*)d_in[0];
    int* bar    = (int*)d_ws;          // barrier counter (ws is poisoned -> must zero)
    int* totals = bar + 16;            // 16 molecule totals at offset 64 B
    float* out  = (float*)d_out;
    int P = out_size / 10;

    hipMemsetAsync(bar, 0, 64, stream);   // capture-legal, stream-ordered
    hipLaunchKernelGGL(fused, dim3(NBLK), dim3(1024), 0, stream,
                       coords, bar, totals, out, P);
}

// Round 5
// 99.131 us; speedup vs baseline: 1.9505x; 1.9505x over previous
//
#include <hip/hip_runtime.h>

#define NMOL 16
#define NAT  512
#define NK   27

// Bit-exact float32 constants matching the numpy reference on host:
//   inv_cell diagonal = 1/20 correctly rounded = 0.05f (0x3D4CCCCD)
//   mask: dist<5.0 with correctly-rounded sqrt  <=>  ss < pred(25.0f) = 0x41C7FFFF
#define SSMAX 24.999998092651367f

__device__ __forceinline__ float wrap1(float v) {
    // proj = rn(v*0.05f); coords in [0,20) => proj<1 => woff=0, frac=proj
    // wrapped = rn(frac*20)
    return __fmul_rn(__fmul_rn(v, 0.05f), 20.0f);
}

// Candidate (unique possible) image per component + exact-mask squared distance
// test. Returns kk in 0..26 on hit, 31 on miss.
__device__ __forceinline__ int probe_code(float wx, float wy, float wz,
                                          float wjx, float wjy, float wjz,
                                          bool self) {
    float dx = __fsub_rn(wx, wjx);
    float dy = __fsub_rn(wy, wjy);
    float dz = __fsub_rn(wz, wjz);
    int ox = (dx > 15.0f) ? -1 : ((dx < -15.0f) ? 1 : 0);
    int oy = (dy > 15.0f) ? -1 : ((dy < -15.0f) ? 1 : 0);
    int oz = (dz > 15.0f) ? -1 : ((dz < -15.0f) ? 1 : 0);
    float ax = __fadd_rn(dx, 20.0f * (float)ox);
    float ay = __fadd_rn(dy, 20.0f * (float)oy);
    float az = __fadd_rn(dz, 20.0f * (float)oz);
    float ss = __fadd_rn(__fadd_rn(__fmul_rn(ax, ax), __fmul_rn(ay, ay)),
                         __fmul_rn(az, az));
    bool hit = (ss < SSMAX) && !self;
    return hit ? ((ox + 1) * 9 + (oy + 1) * 3 + (oz + 1)) : 31;
}

// ---------------- Pass A: count hits per (m, k, i) + per-block totals ----------------
// 1024 blocks x 256 thr; block owns 8 atoms (2 per wave) of one molecule.
// Also stores blkmol[blk] = total hits of this block (plain store, no init needed).
__global__ __launch_bounds__(256, 8) void pass_count(const float* __restrict__ coords,
                                                     int* __restrict__ cnt,
                                                     int* __restrict__ blkmol) {
    __shared__ float rr[NAT * 3];
    __shared__ int cur[2][4][NK];
    const int blk  = blockIdx.x;
    const int m    = blk >> 6;            // 64 blocks per molecule
    const int g0   = (blk & 63) * 2;
    const int t    = threadIdx.x;
    const int w    = t >> 6;
    const int lane = t & 63;
    const int iA   = g0 * 4 + w;
    const int iB   = iA + 4;

    const float4* cm4 = reinterpret_cast<const float4*>(coords + (size_t)m * NAT * 3);
    float4* rr4 = reinterpret_cast<float4*>(rr);
    rr4[t] = cm4[t];                       // 384 float4 total
    if (t < 128) rr4[t + 256] = cm4[t + 256];
    if (t < 2 * 4 * NK) ((int*)cur)[t] = 0;
    __syncthreads();

    const float wAx = wrap1(rr[iA * 3 + 0]), wAy = wrap1(rr[iA * 3 + 1]), wAz = wrap1(rr[iA * 3 + 2]);
    const float wBx = wrap1(rr[iB * 3 + 0]), wBy = wrap1(rr[iB * 3 + 1]), wBz = wrap1(rr[iB * 3 + 2]);

    #pragma unroll
    for (int it = 0; it < NAT / 64; ++it) {
        const int j = it * 64 + lane;
        float wjx = wrap1(rr[j * 3 + 0]);
        float wjy = wrap1(rr[j * 3 + 1]);
        float wjz = wrap1(rr[j * 3 + 2]);
        int cA = probe_code(wAx, wAy, wAz, wjx, wjy, wjz, j == iA);
        int cB = probe_code(wBx, wBy, wBz, wjx, wjy, wjz, j == iB);
        if (cA != 31) atomicAdd(&cur[0][w][cA], 1);
        if (cB != 31) atomicAdd(&cur[1][w][cB], 1);
    }
    __syncthreads();
    if (t < 216) {
        int uu = t / 108, rem = t % 108, ww = rem / 27, k = rem % 27;
        int i = (g0 + uu) * 4 + ww;
        cnt[(m * NK + k) * NAT + i] = cur[uu][ww][k];
    }
    if (w == 0) {                          // block total -> blkmol (plain store)
        int s = 0;
        #pragma unroll
        for (int x = lane; x < 216; x += 64) s += ((int*)cur)[x];
        #pragma unroll
        for (int d = 1; d < 64; d <<= 1) s += __shfl_xor(s, d, 64);
        if (lane == 0) blkmol[blk] = s;
    }
}

// ---------------- Pass B: fused scan + ordered emit ----------------
// 256 blocks x 1024 thr; 16 blocks per molecule, each emits 32 atoms.
// Block loads its molecule's full (k,i) count slice, scans the 27 chunks in
// LDS (verified R3 scan), derives molecule bases from blkmol (wave w reduces
// molecule w's 64 block totals), folds absolute cursors, then runs the
// verified ballot-ordered emit. Cross-kernel sync = hardware dispatch boundary.
__global__ __launch_bounds__(1024, 4) void scan_emit(const float* __restrict__ coords,
                                                     const int* __restrict__ cnt,
                                                     const int* __restrict__ blkmol,
                                                     float* __restrict__ out, int P) {
    __shared__ float rr[NAT * 3];      // 6 KB
    __shared__ int scnt[NK * NAT];     // 55.3 KB: counts -> exclusive -> cursors
    __shared__ int ctot[NK];
    __shared__ int cexcl[NK];
    __shared__ int tls[NMOL];

    const int blk  = blockIdx.x;       // 0..255
    const int m    = blk >> 4;         // molecule
    const int q    = blk & 15;         // 32-atom emit slice
    const int t    = threadIdx.x;      // 0..1023
    const int w    = t >> 6;           // wave 0..15
    const int lane = t & 63;

    // stage raw coords (packed, float4)
    const float4* cm4 = reinterpret_cast<const float4*>(coords + (size_t)m * NAT * 3);
    float4* rr4 = reinterpret_cast<float4*>(rr);
    if (t < 384) rr4[t] = cm4[t];

    // load this molecule's count slice
    const int* cslice = cnt + m * NK * NAT;
    for (int x = t; x < NK * NAT; x += 1024) scnt[x] = cslice[x];

    // molecule totals: wave w reduces blkmol[w*64 .. w*64+63] (64 blocks/molecule)
    {
        int v = blkmol[t];             // t spans exactly the 1024 count blocks
        #pragma unroll
        for (int d = 1; d < 64; d <<= 1) v += __shfl_xor(v, d, 64);
        if (lane == 0) tls[w] = v;
    }
    __syncthreads();

    // per-chunk exclusive scan over 512 atoms, one wave per chunk (verified)
    for (int k = w; k < NK; k += 16) {
        int* ck = scnt + k * NAT;
        int v[8];
        int tot = 0;
        #pragma unroll
        for (int e = 0; e < 8; ++e) { v[e] = ck[lane * 8 + e]; tot += v[e]; }
        int incl = tot;
        #pragma unroll
        for (int d = 1; d < 64; d <<= 1) {
            int u = __shfl_up(incl, d, 64);
            if (lane >= d) incl += u;
        }
        int acc = incl - tot;
        #pragma unroll
        for (int e = 0; e < 8; ++e) { int tmp = v[e]; ck[lane * 8 + e] = acc; acc += tmp; }
        if (lane == 63) ctot[k] = incl;
    }
    __syncthreads();
    if (t == 0) {
        int run = 0;
        for (int mm = 0; mm < m; ++mm) run += tls[mm];   // molecule base
        for (int k = 0; k < NK; ++k) { cexcl[k] = run; run += ctot[k]; }
    }
    __syncthreads();
    // fold absolute bases: scnt becomes the global cursor per (k,i)
    for (int x = t; x < NK * NAT; x += 1024) scnt[x] += cexcl[x >> 9];
    __syncthreads();

    // ---- emit this block's 32 atoms (wave w owns atoms q*32+2w, +2w+1) ----
    const unsigned long long ltmask =
        (lane == 0) ? 0ull : (~0ull >> (64 - lane));

    #pragma unroll
    for (int u = 0; u < 2; ++u) {
        const int i  = q * 32 + 2 * w + u;
        const float rx = rr[i*3+0], ry = rr[i*3+1], rz = rr[i*3+2];
        const float wx = wrap1(rx), wy = wrap1(ry), wz = wrap1(rz);
        const int pf = m * NAT + i;

        #pragma unroll
        for (int it = 0; it < NAT / 64; ++it) {
            const int j = it * 64 + lane;
            const float rjx = rr[j*3+0], rjy = rr[j*3+1], rjz = rr[j*3+2];
            int code = probe_code(wx, wy, wz,
                                  wrap1(rjx), wrap1(rjy), wrap1(rjz), j == i);
            bool hit = (code != 31);
            int kk = hit ? code : 0;

            // match-any over 5-bit kk among hitting lanes
            unsigned long long grp = __ballot(hit);
            #pragma unroll
            for (int b = 0; b < 5; ++b) {
                unsigned long long bm = __ballot((kk >> b) & 1);
                grp &= ((kk >> b) & 1) ? bm : ~bm;
            }
            int leader = hit ? (__ffsll((unsigned long long)grp) - 1) : 0;
            int cntg   = __popcll(grp);
            int rank   = __popcll(grp & ltmask);

            int base = 0;
            if (hit && lane == leader)
                base = atomicAdd(&scnt[kk * NAT + i], cntg);   // ds_add_rtn cursor
            base = __shfl(base, leader, 64);                   // broadcast from leader

            if (hit) {
                int p = base + rank;
                if (p < P) {
                    int ox = kk / 9;
                    int rem = kk - ox * 9;
                    int oy = rem / 3;
                    int oz = rem - oy * 3;
                    ox -= 1; oy -= 1; oz -= 1;
                    float cx = 20.0f * (float)ox;
                    float cy = 20.0f * (float)oy;
                    float cz = 20.0f * (float)oz;
                    float px = __fadd_rn(__fsub_rn(rx, rjx), cx);
                    float py = __fadd_rn(__fsub_rn(ry, rjy), cy);
                    float pz = __fadd_rn(__fsub_rn(rz, rjz), cz);
                    float ss = __fadd_rn(__fadd_rn(__fmul_rn(px, px), __fmul_rn(py, py)),
                                         __fmul_rn(pz, pz));
                    out[p]                 = __fsqrt_rn(ss);        // distflat2
                    out[P + p]             = (float)pf;             // pair_first
                    out[2 * P + p]         = (float)(m * NAT + j);  // pair_second
                    out[3 * P + 3 * p + 0] = px;                    // paircoord
                    out[3 * P + 3 * p + 1] = py;
                    out[3 * P + 3 * p + 2] = pz;
                    out[6 * P + 3 * p + 0] = (float)ox;             // offsets
                    out[6 * P + 3 * p + 1] = (float)oy;
                    out[6 * P + 3 * p + 2] = (float)oz;
                    out[9 * P + p]         = (float)kk;             // offset_index
                }
            }
        }
    }
}

extern "C" void kernel_launch(void* const* d_in, const int* in_sizes, int n_in,
                              void* d_out, int out_size, void* d_ws, size_t ws_size,
                              hipStream_t stream) {
    (void)in_sizes; (void)n_in; (void)ws_size;
    const float* coords = (const float*)d_in[0];
    int* cnt    = (int*)d_ws;              // NMOL*NK*NAT ints
    int* blkmol = cnt + NMOL * NK * NAT;   // 1024 ints (per-count-block totals)
    float* out  = (float*)d_out;
    const int P = out_size / 10;

    hipLaunchKernelGGL(pass_count, dim3(NMOL * NAT / 8), dim3(256), 0, stream,
                       coords, cnt, blkmol);
    hipLaunchKernelGGL(scan_emit, dim3(256), dim3(1024), 0, stream,
                       coords, cnt, blkmol, out, P);
}